// Round 4
// baseline (1167.078 us; speedup 1.0000x reference)
//
#include <hip/hip_runtime.h>
#include <hip/hip_bf16.h>

// Problem dims (fixed by reference)
#define L_DIM 2048
#define B_DIM 8
#define D_DIM 1024
#define M_DIM (L_DIM * B_DIM)   // 16384 rows of x_norm
#define N_DIM (3 * D_DIM)       // 3072
#define K_DIM D_DIM             // 1024
#define BD (B_DIM * D_DIM)      // 8192 independent recurrence chains
#define NCHUNK 64
#define CLEN (L_DIM / NCHUNK)   // 32

typedef __attribute__((ext_vector_type(8))) __bf16 bf16x8;
typedef __attribute__((ext_vector_type(4))) __bf16 bf16x4;
typedef __attribute__((ext_vector_type(4))) float f32x4;

#define GLOAD_LDS16(g, l)                                        \
  __builtin_amdgcn_global_load_lds(                              \
      (const __attribute__((address_space(1))) void*)(g),        \
      (__attribute__((address_space(3))) void*)(l), 16, 0, 0)

__device__ __forceinline__ float sigmoidf_(float v) {
  return 1.0f / (1.0f + __expf(-v));
}

// ---------------------------------------------------------------------------
// Kernel 1: LayerNorm per (l,b) row of D=1024.
// ---------------------------------------------------------------------------
__global__ __launch_bounds__(256) void ln_kernel(
    const float* __restrict__ x, const float* __restrict__ gamma,
    const float* __restrict__ beta, __bf16* __restrict__ xn) {
  const int row = blockIdx.x;
  const int tid = threadIdx.x;
  const float4 v = ((const float4*)(x + (size_t)row * D_DIM))[tid];
  float s  = v.x + v.y + v.z + v.w;
  float ss = v.x * v.x + v.y * v.y + v.z * v.z + v.w * v.w;
  #pragma unroll
  for (int off = 32; off > 0; off >>= 1) {
    s  += __shfl_xor(s, off);
    ss += __shfl_xor(ss, off);
  }
  __shared__ float sb[8];
  const int wid = tid >> 6, lane = tid & 63;
  if (lane == 0) { sb[wid] = s; sb[4 + wid] = ss; }
  __syncthreads();
  const float tot  = sb[0] + sb[1] + sb[2] + sb[3];
  const float tot2 = sb[4] + sb[5] + sb[6] + sb[7];
  const float mu  = tot * (1.0f / D_DIM);
  const float var = tot2 * (1.0f / D_DIM) - mu * mu;
  const float rstd = rsqrtf(var + 1e-5f);
  const float4 g  = ((const float4*)gamma)[tid];
  const float4 bt = ((const float4*)beta)[tid];
  bf16x4 o;
  o[0] = (__bf16)((v.x - mu) * rstd * g.x + bt.x);
  o[1] = (__bf16)((v.y - mu) * rstd * g.y + bt.y);
  o[2] = (__bf16)((v.z - mu) * rstd * g.z + bt.z);
  o[3] = (__bf16)((v.w - mu) * rstd * g.w + bt.w);
  ((bf16x4*)(xn + (size_t)row * D_DIM))[tid] = o;
}

// ---------------------------------------------------------------------------
// Kernel 2: W fp32 -> bf16
// ---------------------------------------------------------------------------
__global__ __launch_bounds__(256) void wconv_kernel(
    const float* __restrict__ W, __bf16* __restrict__ Wb) {
  const size_t i = ((size_t)blockIdx.x * 256 + threadIdx.x) * 4;
  const float4 v = *(const float4*)(W + i);
  bf16x4 o;
  o[0] = (__bf16)v.x; o[1] = (__bf16)v.y; o[2] = (__bf16)v.z; o[3] = (__bf16)v.w;
  *(bf16x4*)(Wb + i) = o;
}

// ---------------------------------------------------------------------------
// Kernel 3: 256x256 GEMM, BK=32, 2-phase pipeline, 2 blocks/CU.
//
// LDS: 2 buffers x 32 KB (A 16K + B 16K) = 64 KB K-loop, 67.6 KB with
// epilogue staging -> 2 blocks/CU (16 waves) so one block's MFMA phases
// overlap the sibling block's LDS/stage phases (m114 mechanism).
//
// Stage unit = (op, half h) = [128 rows][32 elems] 8 KB, all 512 threads,
// 1 gload_lds/thread: tid -> (row=tid>>2, slot=(tid&3)^((row>>1)&3));
// XOR on global SOURCE, LDS linear; frag reads apply same XOR -> <=2-way
// bank aliasing (free). Global: 16 rows x 64B contiguous per instr.
//
// Per tile t (buf = t&1; prefetch tile t+1 into buf^1):
//  P1: rdA m0-3, rdB n0-3 | stage A(t+1) h0,h1 | BAR | 16 MFMA | BAR
//  P2: rdA m4-7           | stage B(t+1) h0,h1 | BAR | 16 MFMA | VMCNT(0) BAR
// Slot safety: A[buf^1] written t.P1, last read (t-1).P2 (2 barriers prior);
// B[buf^1] written t.P2, last read (t-1).P1. Consume: t+1 reads need
// A/B(t+1) landed -> vmcnt(0)+barrier at t.P2-end. Drain stalls are hidden
// by the co-resident block.
// ---------------------------------------------------------------------------
#define VMCNT(n) asm volatile("s_waitcnt vmcnt(" #n ")" ::: "memory")

__global__ __launch_bounds__(512, 4) void gemm256_kernel(
    const __bf16* __restrict__ A,   // [M][K]
    const __bf16* __restrict__ Bm,  // [N][K]
    const float* __restrict__ bias,
    __bf16* __restrict__ U, __bf16* __restrict__ FG, __bf16* __restrict__ RG) {
  __shared__ __bf16 lds[33792];  // 67.6 KB (K-loop uses first 32768)
  const int tid = threadIdx.x;
  const int lane = tid & 63;
  const int wid = tid >> 6;       // 0..7
  const int wm = wid >> 2;        // 0..1  (row-half)
  const int wn = wid & 3;         // 0..3  (col quarter)
  const int g2 = wn >> 1;         // B row-half this wave reads

  // XCD-bijective swizzle: 768 blocks, 768 % 8 == 0.
  const int bid0 = blockIdx.x;
  const int bid = (bid0 & 7) * 96 + (bid0 >> 3);
  const int bm = bid / 12, bn = bid % 12;

#define AUNIT(buf, h) ((buf) * 16384 + (h) * 4096)
#define BUNIT(buf, h) ((buf) * 16384 + 8192 + (h) * 4096)

  // Staging: one 16B load per thread per unit, coalesced 64B/row globally.
  const int srow  = tid >> 2;                       // 0..127
  const int sslot = (tid & 3) ^ ((srow >> 1) & 3);  // swizzled 16B slot
  auto stageA = [&](int kt2, int h) {
    const __bf16* gs = A + (size_t)(bm * 256 + h * 128 + srow) * K_DIM +
                       kt2 * 32 + sslot * 8;
    GLOAD_LDS16(gs, lds + AUNIT(kt2 & 1, h) + tid * 8);
  };
  auto stageB = [&](int kt2, int h) {
    const __bf16* gs = Bm + (size_t)(bn * 256 + h * 128 + srow) * K_DIM +
                       kt2 * 32 + sslot * 8;
    GLOAD_LDS16(gs, lds + BUNIT(kt2 & 1, h) + tid * 8);
  };

  const int fr = lane & 15, fk = lane >> 4;
  const int swz = fk ^ ((fr >> 1) & 3);             // undo source swizzle
  auto rdA = [&](int buf, int m) {
    return *(const bf16x8*)(lds + AUNIT(buf, wm) + (m * 16 + fr) * 32 +
                            swz * 8);
  };
  auto rdB = [&](int buf, int n) {
    return *(const bf16x8*)(lds + BUNIT(buf, g2) +
                            ((wn & 1) * 64 + n * 16 + fr) * 32 + swz * 8);
  };

  f32x4 acc[8][4] = {};

  // Prologue: stage tile 0 fully; drain; sync.
  stageA(0, 0); stageA(0, 1); stageB(0, 0); stageB(0, 1);
  VMCNT(0);
  __builtin_amdgcn_s_barrier();

  #pragma unroll 1
  for (int kt = 0; kt < 32; ++kt) {
    const int buf = kt & 1;
    bf16x8 a[4], b[4];

    // ---- P1: m 0-3 ----
    #pragma unroll
    for (int m = 0; m < 4; ++m) a[m] = rdA(buf, m);
    #pragma unroll
    for (int n = 0; n < 4; ++n) b[n] = rdB(buf, n);
    if (kt < 31) { stageA(kt + 1, 0); stageA(kt + 1, 1); }
    __builtin_amdgcn_s_barrier();
    __builtin_amdgcn_s_setprio(1);
    #pragma unroll
    for (int m = 0; m < 4; ++m)
      #pragma unroll
      for (int n = 0; n < 4; ++n)
        acc[m][n] = __builtin_amdgcn_mfma_f32_16x16x32_bf16(a[m], b[n],
                                                            acc[m][n], 0, 0, 0);
    __builtin_amdgcn_s_setprio(0);
    __builtin_amdgcn_s_barrier();

    // ---- P2: m 4-7 ----
    #pragma unroll
    for (int m = 0; m < 4; ++m) a[m] = rdA(buf, m + 4);
    if (kt < 31) { stageB(kt + 1, 0); stageB(kt + 1, 1); }
    __builtin_amdgcn_s_barrier();
    __builtin_amdgcn_s_setprio(1);
    #pragma unroll
    for (int m = 0; m < 4; ++m)
      #pragma unroll
      for (int n = 0; n < 4; ++n)
        acc[m + 4][n] = __builtin_amdgcn_mfma_f32_16x16x32_bf16(
            a[m], b[n], acc[m + 4][n], 0, 0, 0);
    __builtin_amdgcn_s_setprio(0);
    VMCNT(0);                      // tile t+1 fully landed before next reads
    __builtin_amdgcn_s_barrier();
  }

  // Epilogue: acc -> LDS (bf16, [128 rows][264 cols], 2 half-phases) ->
  // coalesced dwordx4 stores. All staging loads drained.
  const int seg = bn >> 2;  // 0:u 1:f 2:r
  __bf16* outb = (seg == 0) ? U : ((seg == 1) ? FG : RG);
  const int segcol0 = (bn & 3) * 256;

  float bv[4];
  #pragma unroll
  for (int n = 0; n < 4; ++n)
    bv[n] = bias[seg * 1024 + segcol0 + wn * 64 + n * 16 + fr];

  const int lrow = tid >> 5;        // 0..15 (readback)
  const int chunk = tid & 31;       // 16B chunk within 512B row
  #pragma unroll 1
  for (int h = 0; h < 2; ++h) {
    __syncthreads();
    if (wm == h) {
      #pragma unroll
      for (int m = 0; m < 8; ++m)
        #pragma unroll
        for (int n = 0; n < 4; ++n)
          #pragma unroll
          for (int j = 0; j < 4; ++j) {
            float v = acc[m][n][j] + bv[n];
            if (seg != 0) v = sigmoidf_(v);
            lds[(m * 16 + fk * 4 + j) * 264 + wn * 64 + n * 16 + fr] =
                (__bf16)v;
          }
    }
    __syncthreads();
    #pragma unroll
    for (int it = 0; it < 8; ++it) {
      const int r = it * 16 + lrow;
      const bf16x8 val = *(const bf16x8*)(lds + r * 264 + chunk * 8);
      const size_t grow = (size_t)(bm * 256 + h * 128 + r);
      *(bf16x8*)(outb + grow * D_DIM + segcol0 + chunk * 8) = val;
    }
  }
}

// ---------------------------------------------------------------------------
// Scan pass A: per (chunk, bd) affine composition over CLEN steps.
// ---------------------------------------------------------------------------
__global__ __launch_bounds__(256) void scanA_kernel(
    const __bf16* __restrict__ fg, const __bf16* __restrict__ u,
    float* __restrict__ av) {
  const int ci = blockIdx.x;
  const int bd = blockIdx.y * 256 + threadIdx.x;
  float a = 1.0f, v = 0.0f;
  const size_t base = (size_t)ci * CLEN * BD + bd;
  #pragma unroll 8
  for (int i = 0; i < CLEN; ++i) {
    const size_t idx = base + (size_t)i * BD;
    const float f = (float)fg[idx];
    const float uu = (float)u[idx];
    a *= f;
    v = f * v + (1.0f - f) * uu;
  }
  av[(size_t)ci * BD + bd] = a;
  av[(size_t)NCHUNK * BD + (size_t)ci * BD + bd] = v;
}

// ---------------------------------------------------------------------------
// Scan pass B: sequential combine across chunks; writes last_c.
// ---------------------------------------------------------------------------
__global__ __launch_bounds__(256) void scanB_kernel(
    const float* __restrict__ av, const float* __restrict__ c0,
    float* __restrict__ carries, float* __restrict__ out1) {
  const int bd = blockIdx.x * 256 + threadIdx.x;
  float c = c0[bd];
  #pragma unroll 8
  for (int ci = 0; ci < NCHUNK; ++ci) {
    carries[(size_t)ci * BD + bd] = c;
    c = av[(size_t)ci * BD + bd] * c + av[(size_t)NCHUNK * BD + (size_t)ci * BD + bd];
  }
  out1[bd] = c;
}

// ---------------------------------------------------------------------------
// Scan pass C: re-run recurrence within chunk, fuse hs + residual.
// ---------------------------------------------------------------------------
__global__ __launch_bounds__(256) void scanC_kernel(
    const __bf16* __restrict__ fg, const __bf16* __restrict__ u,
    const __bf16* __restrict__ rg, const __bf16* __restrict__ xn,
    const float* __restrict__ x, const float* __restrict__ carries,
    float* __restrict__ out0) {
  const int ci = blockIdx.x;
  const int bd = blockIdx.y * 256 + threadIdx.x;
  float c = carries[(size_t)ci * BD + bd];
  const size_t base = (size_t)ci * CLEN * BD + bd;
  #pragma unroll 4
  for (int i = 0; i < CLEN; ++i) {
    const size_t idx = base + (size_t)i * BD;
    const float f = (float)fg[idx];
    const float uu = (float)u[idx];
    c = f * c + (1.0f - f) * uu;
    const float r = (float)rg[idx];
    const float xnv = (float)xn[idx];
    const float hs = r * tanhf(c) + (1.0f - r) * xnv;
    out0[idx] = x[idx] + hs;
  }
}

// ---------------------------------------------------------------------------
extern "C" void kernel_launch(void* const* d_in, const int* in_sizes, int n_in,
                              void* d_out, int out_size, void* d_ws,
                              size_t ws_size, hipStream_t stream) {
  const float* x     = (const float*)d_in[0];
  const float* c0    = (const float*)d_in[1];
  const float* W     = (const float*)d_in[2];
  const float* bias  = (const float*)d_in[3];
  const float* gamma = (const float*)d_in[4];
  const float* beta  = (const float*)d_in[5];

  float* out0 = (float*)d_out;                 // [L,B,D]
  float* out1 = out0 + (size_t)M_DIM * D_DIM;  // [B,D]

  char* ws = (char*)d_ws;
  __bf16* xn = (__bf16*)(ws + 0);              // 32 MB
  __bf16* Wb = (__bf16*)(ws + 33554432);       //  6 MB
  __bf16* U  = (__bf16*)(ws + 39845888);       // 32 MB
  __bf16* FG = (__bf16*)(ws + 73400320);       // 32 MB
  __bf16* RG = (__bf16*)(ws + 106954752);      // 32 MB
  float* av      = (float*)(ws + 140509184);   //  4 MB
  float* carries = (float*)(ws + 144703488);   //  2 MB

  ln_kernel<<<M_DIM, 256, 0, stream>>>(x, gamma, beta, xn);
  wconv_kernel<<<(N_DIM * K_DIM / 4) / 256, 256, 0, stream>>>(W, Wb);
  gemm256_kernel<<<(M_DIM / 256) * (N_DIM / 256), 512, 0, stream>>>(
      xn, Wb, bias, U, FG, RG);
  scanA_kernel<<<dim3(NCHUNK, BD / 256), 256, 0, stream>>>(FG, U, av);
  scanB_kernel<<<BD / 256, 256, 0, stream>>>(av, c0, carries, out1);
  scanC_kernel<<<dim3(NCHUNK, BD / 256), 256, 0, stream>>>(
      FG, U, RG, xn, x, carries, out0);
}

// Round 5
// 228.216 us; speedup vs baseline: 5.1139x; 5.1139x over previous
//
#include <hip/hip_runtime.h>
#include <hip/hip_bf16.h>

// Problem dims (fixed by reference)
#define L_DIM 2048
#define B_DIM 8
#define D_DIM 1024
#define M_DIM (L_DIM * B_DIM)   // 16384 rows of x_norm
#define N_DIM (3 * D_DIM)       // 3072
#define K_DIM D_DIM             // 1024
#define BD (B_DIM * D_DIM)      // 8192 independent recurrence chains
#define NCHUNK 64
#define CLEN (L_DIM / NCHUNK)   // 32

typedef __attribute__((ext_vector_type(8))) __bf16 bf16x8;
typedef __attribute__((ext_vector_type(4))) __bf16 bf16x4;
typedef __attribute__((ext_vector_type(4))) float f32x4;

#define GLOAD_LDS16(g, l)                                        \
  __builtin_amdgcn_global_load_lds(                              \
      (const __attribute__((address_space(1))) void*)(g),        \
      (__attribute__((address_space(3))) void*)(l), 16, 0, 0)

__device__ __forceinline__ float sigmoidf_(float v) {
  return 1.0f / (1.0f + __expf(-v));
}

// ---------------------------------------------------------------------------
// Kernel 1: LayerNorm per (l,b) row of D=1024.
// ---------------------------------------------------------------------------
__global__ __launch_bounds__(256) void ln_kernel(
    const float* __restrict__ x, const float* __restrict__ gamma,
    const float* __restrict__ beta, __bf16* __restrict__ xn) {
  const int row = blockIdx.x;
  const int tid = threadIdx.x;
  const float4 v = ((const float4*)(x + (size_t)row * D_DIM))[tid];
  float s  = v.x + v.y + v.z + v.w;
  float ss = v.x * v.x + v.y * v.y + v.z * v.z + v.w * v.w;
  #pragma unroll
  for (int off = 32; off > 0; off >>= 1) {
    s  += __shfl_xor(s, off);
    ss += __shfl_xor(ss, off);
  }
  __shared__ float sb[8];
  const int wid = tid >> 6, lane = tid & 63;
  if (lane == 0) { sb[wid] = s; sb[4 + wid] = ss; }
  __syncthreads();
  const float tot  = sb[0] + sb[1] + sb[2] + sb[3];
  const float tot2 = sb[4] + sb[5] + sb[6] + sb[7];
  const float mu  = tot * (1.0f / D_DIM);
  const float var = tot2 * (1.0f / D_DIM) - mu * mu;
  const float rstd = rsqrtf(var + 1e-5f);
  const float4 g  = ((const float4*)gamma)[tid];
  const float4 bt = ((const float4*)beta)[tid];
  bf16x4 o;
  o[0] = (__bf16)((v.x - mu) * rstd * g.x + bt.x);
  o[1] = (__bf16)((v.y - mu) * rstd * g.y + bt.y);
  o[2] = (__bf16)((v.z - mu) * rstd * g.z + bt.z);
  o[3] = (__bf16)((v.w - mu) * rstd * g.w + bt.w);
  ((bf16x4*)(xn + (size_t)row * D_DIM))[tid] = o;
}

// ---------------------------------------------------------------------------
// Kernel 2: W fp32 -> bf16
// ---------------------------------------------------------------------------
__global__ __launch_bounds__(256) void wconv_kernel(
    const float* __restrict__ W, __bf16* __restrict__ Wb) {
  const size_t i = ((size_t)blockIdx.x * 256 + threadIdx.x) * 4;
  const float4 v = *(const float4*)(W + i);
  bf16x4 o;
  o[0] = (__bf16)v.x; o[1] = (__bf16)v.y; o[2] = (__bf16)v.z; o[3] = (__bf16)v.w;
  *(bf16x4*)(Wb + i) = o;
}

// ---------------------------------------------------------------------------
// Kernel 3: 256x128 GEMM, BK=32, TRIPLE-buffered, 1 barrier/tile, vmcnt(3).
//
// 8 waves in 4x2 grid (wq=row quarter of 64, wc=col half of 64): per-wave
// acc[4][4] = 64 VGPR -> total ~116 VGPR <= 128 -> 16 waves/CU (2 blocks).
// LDS = 3 bufs x (A 256x32 + B 128x32) = 72 KB -> 144 KB/CU for 2 blocks.
//
// Pipeline invariant: entering tile t, only stage(t-1)->buf[(t+1)%3] is
// outstanding. Tile t: issue stage(t+2)->buf[(t+2)%3]; read buf[t%3];
// 16 MFMA; vmcnt(3) (drains stage(t-1) exactly -> tile t+1 ready); barrier.
// Buffers {t,t+1,t+2} pairwise distinct mod 3 -> stage never races reads;
// the single trailing barrier of t-1 orders stage(t+2) after reads(t-1) of
// the same physical buffer. Tail: t=30 vmcnt(0); t=31 none.
// Prologue: stage t0,t1; vmcnt(3); barrier.
//
// Staging (per 8KB/16KB unit): tid -> chunk c (row=c>>2,
// slot=(c&3)^((row>>1)&3)); XOR on global SOURCE, LDS linear; frag reads
// apply the same XOR (swz) -> measured 0 bank conflicts (r3/r4). Global
// pattern: 4 rows x 64 B contiguous per 16 lanes.
// ---------------------------------------------------------------------------
#define VMCNT(n) asm volatile("s_waitcnt vmcnt(" #n ")" ::: "memory")

__global__ __launch_bounds__(512, 4) void gemm256_kernel(
    const __bf16* __restrict__ A,   // [M][K]
    const __bf16* __restrict__ Bm,  // [N][K]
    const float* __restrict__ bias,
    __bf16* __restrict__ U, __bf16* __restrict__ FG, __bf16* __restrict__ RG) {
  __shared__ __bf16 lds[36864];   // 72 KB; epilogue reuses first 34.8 KB
  const int tid = threadIdx.x;
  const int lane = tid & 63;
  const int wid = tid >> 6;       // 0..7
  const int wq = wid >> 1;        // 0..3  row quarter (64 rows)
  const int wc = wid & 1;         // 0..1  col half   (64 cols)

  // XCD-bijective swizzle: 1536 blocks, 1536 % 8 == 0. bn fastest -> the 24
  // blocks sharing an A panel are consecutive on one XCD (A panel L2-hot).
  const int bid0 = blockIdx.x;
  const int bid = (bid0 & 7) * 192 + (bid0 >> 3);
  const int bm = bid / 24, bn = bid % 24;

#define BUFO(p) ((p) * 12288)     // A at +0 (8192 elems), B at +8192 (4096)

  const int srow  = tid >> 2;                       // 0..127
  const int sslot = (tid & 3) ^ ((srow >> 1) & 3);  // swizzled 16B slot
  // A unit: 256 rows x 32 elems = 1024 chunks; thread does c=tid, c=tid+512.
  auto stageA = [&](int kt2, int p) {
    const __bf16* gs = A + (size_t)(bm * 256 + srow) * K_DIM + kt2 * 32 +
                       sslot * 8;
    GLOAD_LDS16(gs, lds + BUFO(p) + tid * 8);
    GLOAD_LDS16(gs + (size_t)128 * K_DIM, lds + BUFO(p) + (tid + 512) * 8);
  };
  // B unit: 128 rows x 32 elems = 512 chunks; thread does c=tid.
  auto stageB = [&](int kt2, int p) {
    const __bf16* gs = Bm + (size_t)(bn * 128 + srow) * K_DIM + kt2 * 32 +
                       sslot * 8;
    GLOAD_LDS16(gs, lds + BUFO(p) + 8192 + tid * 8);
  };

  const int fr = lane & 15, fk = lane >> 4;
  const int swz = fk ^ ((fr >> 1) & 3);             // undo source swizzle
  auto rdA = [&](int p, int m) {
    return *(const bf16x8*)(lds + BUFO(p) + (wq * 64 + m * 16 + fr) * 32 +
                            swz * 8);
  };
  auto rdB = [&](int p, int n) {
    return *(const bf16x8*)(lds + BUFO(p) + 8192 +
                            (wc * 64 + n * 16 + fr) * 32 + swz * 8);
  };

  f32x4 acc[4][4] = {};

  // Prologue: stage tiles 0 and 1; vmcnt(3) -> tile0 landed, tile1 in flight.
  stageA(0, 0); stageB(0, 0);
  stageA(1, 1); stageB(1, 1);
  VMCNT(3);
  __builtin_amdgcn_s_barrier();

  int pc = 0;  // buf of current tile
  #pragma unroll 1
  for (int kt = 0; kt < 32; ++kt) {
    const int ps = pc >= 1 ? pc - 1 : 2;  // (pc+2)%3, buf for tile kt+2
    if (kt <= 29) { stageA(kt + 2, ps); stageB(kt + 2, ps); }

    bf16x8 a[4], b[4];
    #pragma unroll
    for (int m = 0; m < 4; ++m) a[m] = rdA(pc, m);
    #pragma unroll
    for (int n = 0; n < 4; ++n) b[n] = rdB(pc, n);

    __builtin_amdgcn_s_setprio(1);
    #pragma unroll
    for (int m = 0; m < 4; ++m)
      #pragma unroll
      for (int n = 0; n < 4; ++n)
        acc[m][n] = __builtin_amdgcn_mfma_f32_16x16x32_bf16(a[m], b[n],
                                                            acc[m][n], 0, 0, 0);
    __builtin_amdgcn_s_setprio(0);

    if (kt <= 29) { VMCNT(3); }        // drains stage(kt-1): tile kt+1 ready
    else if (kt == 30) { VMCNT(0); }   // tail: tile 31 fully landed
    __builtin_amdgcn_s_barrier();
    pc = pc == 2 ? 0 : pc + 1;
  }

  // Epilogue: acc -> LDS (bf16, [128 rows][136 cols], 2 half-phases) ->
  // coalesced 16B stores. All staging loads drained (vmcnt(0) at kt=30).
  const int seg = bn >> 3;  // 0:u 1:f 2:r (128-wide tiles lie in one segment)
  __bf16* outb = (seg == 0) ? U : ((seg == 1) ? FG : RG);
  const int segcol0 = (bn & 7) * 128;

  float bv[4];
  #pragma unroll
  for (int n = 0; n < 4; ++n)
    bv[n] = bias[seg * 1024 + segcol0 + wc * 64 + n * 16 + fr];

  const int lrow = tid >> 4;        // 0..31 (readback)
  const int chunk = tid & 15;       // 16B chunk within 256B row
  #pragma unroll 1
  for (int h = 0; h < 2; ++h) {
    __syncthreads();
    if ((wq >> 1) == h) {
      const int lr0 = (wq & 1) * 64 + fk * 4;
      #pragma unroll
      for (int m = 0; m < 4; ++m)
        #pragma unroll
        for (int n = 0; n < 4; ++n)
          #pragma unroll
          for (int j = 0; j < 4; ++j) {
            float v = acc[m][n][j] + bv[n];
            if (seg != 0) v = sigmoidf_(v);
            lds[(lr0 + m * 16 + j) * 136 + wc * 64 + n * 16 + fr] = (__bf16)v;
          }
    }
    __syncthreads();
    #pragma unroll
    for (int it = 0; it < 4; ++it) {
      const int r = it * 32 + lrow;
      const bf16x8 val = *(const bf16x8*)(lds + r * 136 + chunk * 8);
      const size_t grow = (size_t)(bm * 256 + h * 128 + r);
      *(bf16x8*)(outb + grow * D_DIM + segcol0 + chunk * 8) = val;
    }
  }
}

// ---------------------------------------------------------------------------
// Scan pass A: per (chunk, bd) affine composition over CLEN steps.
// ---------------------------------------------------------------------------
__global__ __launch_bounds__(256) void scanA_kernel(
    const __bf16* __restrict__ fg, const __bf16* __restrict__ u,
    float* __restrict__ av) {
  const int ci = blockIdx.x;
  const int bd = blockIdx.y * 256 + threadIdx.x;
  float a = 1.0f, v = 0.0f;
  const size_t base = (size_t)ci * CLEN * BD + bd;
  #pragma unroll 8
  for (int i = 0; i < CLEN; ++i) {
    const size_t idx = base + (size_t)i * BD;
    const float f = (float)fg[idx];
    const float uu = (float)u[idx];
    a *= f;
    v = f * v + (1.0f - f) * uu;
  }
  av[(size_t)ci * BD + bd] = a;
  av[(size_t)NCHUNK * BD + (size_t)ci * BD + bd] = v;
}

// ---------------------------------------------------------------------------
// Scan pass B: sequential combine across chunks; writes last_c.
// ---------------------------------------------------------------------------
__global__ __launch_bounds__(256) void scanB_kernel(
    const float* __restrict__ av, const float* __restrict__ c0,
    float* __restrict__ carries, float* __restrict__ out1) {
  const int bd = blockIdx.x * 256 + threadIdx.x;
  float c = c0[bd];
  #pragma unroll 8
  for (int ci = 0; ci < NCHUNK; ++ci) {
    carries[(size_t)ci * BD + bd] = c;
    c = av[(size_t)ci * BD + bd] * c + av[(size_t)NCHUNK * BD + (size_t)ci * BD + bd];
  }
  out1[bd] = c;
}

// ---------------------------------------------------------------------------
// Scan pass C: re-run recurrence within chunk, fuse hs + residual.
// ---------------------------------------------------------------------------
__global__ __launch_bounds__(256) void scanC_kernel(
    const __bf16* __restrict__ fg, const __bf16* __restrict__ u,
    const __bf16* __restrict__ rg, const __bf16* __restrict__ xn,
    const float* __restrict__ x, const float* __restrict__ carries,
    float* __restrict__ out0) {
  const int ci = blockIdx.x;
  const int bd = blockIdx.y * 256 + threadIdx.x;
  float c = carries[(size_t)ci * BD + bd];
  const size_t base = (size_t)ci * CLEN * BD + bd;
  #pragma unroll 4
  for (int i = 0; i < CLEN; ++i) {
    const size_t idx = base + (size_t)i * BD;
    const float f = (float)fg[idx];
    const float uu = (float)u[idx];
    c = f * c + (1.0f - f) * uu;
    const float r = (float)rg[idx];
    const float xnv = (float)xn[idx];
    const float hs = r * tanhf(c) + (1.0f - r) * xnv;
    out0[idx] = x[idx] + hs;
  }
}

// ---------------------------------------------------------------------------
extern "C" void kernel_launch(void* const* d_in, const int* in_sizes, int n_in,
                              void* d_out, int out_size, void* d_ws,
                              size_t ws_size, hipStream_t stream) {
  const float* x     = (const float*)d_in[0];
  const float* c0    = (const float*)d_in[1];
  const float* W     = (const float*)d_in[2];
  const float* bias  = (const float*)d_in[3];
  const float* gamma = (const float*)d_in[4];
  const float* beta  = (const float*)d_in[5];

  float* out0 = (float*)d_out;                 // [L,B,D]
  float* out1 = out0 + (size_t)M_DIM * D_DIM;  // [B,D]

  char* ws = (char*)d_ws;
  __bf16* xn = (__bf16*)(ws + 0);              // 32 MB
  __bf16* Wb = (__bf16*)(ws + 33554432);       //  6 MB
  __bf16* U  = (__bf16*)(ws + 39845888);       // 32 MB
  __bf16* FG = (__bf16*)(ws + 73400320);       // 32 MB
  __bf16* RG = (__bf16*)(ws + 106954752);      // 32 MB
  float* av      = (float*)(ws + 140509184);   //  4 MB
  float* carries = (float*)(ws + 144703488);   //  2 MB

  ln_kernel<<<M_DIM, 256, 0, stream>>>(x, gamma, beta, xn);
  wconv_kernel<<<(N_DIM * K_DIM / 4) / 256, 256, 0, stream>>>(W, Wb);
  gemm256_kernel<<<(M_DIM / 256) * (N_DIM / 128), 512, 0, stream>>>(
      xn, Wb, bias, U, FG, RG);
  scanA_kernel<<<dim3(NCHUNK, BD / 256), 256, 0, stream>>>(FG, U, av);
  scanB_kernel<<<BD / 256, 256, 0, stream>>>(av, c0, carries, out1);
  scanC_kernel<<<dim3(NCHUNK, BD / 256), 256, 0, stream>>>(
      FG, U, RG, xn, x, carries, out0);
}

// Round 6
// 227.797 us; speedup vs baseline: 5.1233x; 1.0018x over previous
//
#include <hip/hip_runtime.h>
#include <hip/hip_bf16.h>

// Problem dims (fixed by reference)
#define L_DIM 2048
#define B_DIM 8
#define D_DIM 1024
#define M_DIM (L_DIM * B_DIM)   // 16384 rows of x_norm
#define N_DIM (3 * D_DIM)       // 3072
#define K_DIM D_DIM             // 1024
#define BD (B_DIM * D_DIM)      // 8192 independent recurrence chains
#define NCHUNK 64
#define CLEN (L_DIM / NCHUNK)   // 32

typedef __attribute__((ext_vector_type(8))) __bf16 bf16x8;
typedef __attribute__((ext_vector_type(4))) __bf16 bf16x4;
typedef __attribute__((ext_vector_type(4))) float f32x4;

#define GLOAD_LDS16(g, l)                                        \
  __builtin_amdgcn_global_load_lds(                              \
      (const __attribute__((address_space(1))) void*)(g),        \
      (__attribute__((address_space(3))) void*)(l), 16, 0, 0)

__device__ __forceinline__ float sigmoidf_(float v) {
  return 1.0f / (1.0f + __expf(-v));
}

// ---------------------------------------------------------------------------
// Kernel 1: LayerNorm per (l,b) row of D=1024.
// ---------------------------------------------------------------------------
__global__ __launch_bounds__(256) void ln_kernel(
    const float* __restrict__ x, const float* __restrict__ gamma,
    const float* __restrict__ beta, __bf16* __restrict__ xn) {
  const int row = blockIdx.x;
  const int tid = threadIdx.x;
  const float4 v = ((const float4*)(x + (size_t)row * D_DIM))[tid];
  float s  = v.x + v.y + v.z + v.w;
  float ss = v.x * v.x + v.y * v.y + v.z * v.z + v.w * v.w;
  #pragma unroll
  for (int off = 32; off > 0; off >>= 1) {
    s  += __shfl_xor(s, off);
    ss += __shfl_xor(ss, off);
  }
  __shared__ float sb[8];
  const int wid = tid >> 6, lane = tid & 63;
  if (lane == 0) { sb[wid] = s; sb[4 + wid] = ss; }
  __syncthreads();
  const float tot  = sb[0] + sb[1] + sb[2] + sb[3];
  const float tot2 = sb[4] + sb[5] + sb[6] + sb[7];
  const float mu  = tot * (1.0f / D_DIM);
  const float var = tot2 * (1.0f / D_DIM) - mu * mu;
  const float rstd = rsqrtf(var + 1e-5f);
  const float4 g  = ((const float4*)gamma)[tid];
  const float4 bt = ((const float4*)beta)[tid];
  bf16x4 o;
  o[0] = (__bf16)((v.x - mu) * rstd * g.x + bt.x);
  o[1] = (__bf16)((v.y - mu) * rstd * g.y + bt.y);
  o[2] = (__bf16)((v.z - mu) * rstd * g.z + bt.z);
  o[3] = (__bf16)((v.w - mu) * rstd * g.w + bt.w);
  ((bf16x4*)(xn + (size_t)row * D_DIM))[tid] = o;
}

// ---------------------------------------------------------------------------
// Kernel 2: W fp32 -> bf16
// ---------------------------------------------------------------------------
__global__ __launch_bounds__(256) void wconv_kernel(
    const float* __restrict__ W, __bf16* __restrict__ Wb) {
  const size_t i = ((size_t)blockIdx.x * 256 + threadIdx.x) * 4;
  const float4 v = *(const float4*)(W + i);
  bf16x4 o;
  o[0] = (__bf16)v.x; o[1] = (__bf16)v.y; o[2] = (__bf16)v.z; o[3] = (__bf16)v.w;
  *(bf16x4*)(Wb + i) = o;
}

// ---------------------------------------------------------------------------
// Kernel 3: 256x128 GEMM, 4 waves (2x2), per-wave 128x64 (acc[8][4]),
// BK=32, TRIPLE-buffered, 1 barrier/tile, counted vmcnt(6).
//
// Why per-wave 128x64: A-frag reads amortize over 8 m-tiles -> per wave per
// tile 12 ds_read_b128 : 32 MFMA (0.375 reads/MFMA vs 0.5 at 64x64). Per-CU
// LDS demand ~1536 cyc vs matrix 1242 per tile-pair -> near-balanced.
// VGPR: acc 128 + frags ~64 + addr -> ~220 <= 256 (2 waves/SIMD). LDS 72 KB
// -> 2 blocks/CU = two independent barrier domains (anti-phase overlap).
//
// Pipeline invariant (6 loads/thread/tile: A 4 + B 2): entering tile t only
// stage(t+1)=6 outstanding. Tile t: issue stage(t+2) -> buf[(t+2)%3]; read
// buf[t%3]; 32 MFMA; vmcnt(6) drains stage(t+1) exactly; barrier.
// Tail: kt=30 vmcnt(0); kt=31 none. Prologue: stage t0,t1; vmcnt(6); bar.
// Hazards: bufs {t,t+1,t+2} pairwise distinct mod 3; stage(t+2) vs last
// reads of same buf (at t-1) ordered by t-1's trailing barrier.
//
// Staging: chunk c of a unit -> row=c>>2, slot=(c&3)^(((c>>3))&3... ) i.e.
// slot XOR ((row>>1)&3); thread covers c = tid + 256*i (slot XOR invariant
// since 64*i rows ≡ 0 mod 4). XOR applied on global SOURCE, LDS linear;
// frag reads apply same XOR (swz) -> measured ~0 bank conflicts (r3-r5).
// ---------------------------------------------------------------------------
#define VMCNT(n) asm volatile("s_waitcnt vmcnt(" #n ")" ::: "memory")

__global__ __launch_bounds__(256, 2) void gemm256_kernel(
    const __bf16* __restrict__ A,   // [M][K]
    const __bf16* __restrict__ Bm,  // [N][K]
    const float* __restrict__ bias,
    __bf16* __restrict__ U, __bf16* __restrict__ FG, __bf16* __restrict__ RG) {
  __shared__ __bf16 lds[36864];   // 72 KB; epilogue reuses first 34.8 KB
  const int tid = threadIdx.x;
  const int lane = tid & 63;
  const int wid = tid >> 6;       // 0..3
  const int wm = wid >> 1;        // 0..1  row half (128 rows)
  const int wc = wid & 1;         // 0..1  col half (64 cols)

  // XCD-bijective swizzle: 1536 blocks, 1536 % 8 == 0. bn fastest -> the 24
  // blocks sharing an A panel are consecutive on one XCD (A panel L2-hot).
  const int bid0 = blockIdx.x;
  const int bid = (bid0 & 7) * 192 + (bid0 >> 3);
  const int bm = bid / 24, bn = bid % 24;

#define BUFO(p) ((p) * 12288)     // A at +0 (8192 elems), B at +8192 (4096)

  const int srow  = tid >> 2;                       // 0..63
  const int sslot = (tid & 3) ^ ((srow >> 1) & 3);  // swizzled 16B slot
  // A unit: 256 rows x 32 elems = 1024 chunks; thread does c = tid + 256*i.
  auto stageA = [&](int kt2, int p) {
    const __bf16* gs = A + (size_t)(bm * 256 + srow) * K_DIM + kt2 * 32 +
                       sslot * 8;
    #pragma unroll
    for (int i = 0; i < 4; ++i)
      GLOAD_LDS16(gs + (size_t)(64 * i) * K_DIM,
                  lds + BUFO(p) + (tid + 256 * i) * 8);
  };
  // B unit: 128 rows x 32 elems = 512 chunks; thread does c = tid + 256*i.
  auto stageB = [&](int kt2, int p) {
    const __bf16* gs = Bm + (size_t)(bn * 128 + srow) * K_DIM + kt2 * 32 +
                       sslot * 8;
    #pragma unroll
    for (int i = 0; i < 2; ++i)
      GLOAD_LDS16(gs + (size_t)(64 * i) * K_DIM,
                  lds + BUFO(p) + 8192 + (tid + 256 * i) * 8);
  };

  const int fr = lane & 15, fk = lane >> 4;
  const int swz = fk ^ ((fr >> 1) & 3);             // undo source swizzle
  auto rdA = [&](int p, int m) {
    return *(const bf16x8*)(lds + BUFO(p) +
                            (wm * 128 + m * 16 + fr) * 32 + swz * 8);
  };
  auto rdB = [&](int p, int n) {
    return *(const bf16x8*)(lds + BUFO(p) + 8192 +
                            (wc * 64 + n * 16 + fr) * 32 + swz * 8);
  };

  f32x4 acc[8][4] = {};

  // Prologue: stage tiles 0,1; vmcnt(6) -> tile0 landed, tile1 in flight.
  stageA(0, 0); stageB(0, 0);
  stageA(1, 1); stageB(1, 1);
  VMCNT(6);
  __builtin_amdgcn_s_barrier();

  int pc = 0;  // buf of current tile
  #pragma unroll 1
  for (int kt = 0; kt < 32; ++kt) {
    const int ps = pc >= 1 ? pc - 1 : 2;  // (pc+2)%3, buf for tile kt+2
    if (kt <= 29) { stageA(kt + 2, ps); stageB(kt + 2, ps); }

    bf16x8 a[4], b[4];
    #pragma unroll
    for (int m = 0; m < 4; ++m) a[m] = rdA(pc, m);
    #pragma unroll
    for (int n = 0; n < 4; ++n) b[n] = rdB(pc, n);
    __builtin_amdgcn_s_setprio(1);
    #pragma unroll
    for (int m = 0; m < 4; ++m)
      #pragma unroll
      for (int n = 0; n < 4; ++n)
        acc[m][n] = __builtin_amdgcn_mfma_f32_16x16x32_bf16(a[m], b[n],
                                                            acc[m][n], 0, 0, 0);
    __builtin_amdgcn_s_setprio(0);
    #pragma unroll
    for (int m = 0; m < 4; ++m) a[m] = rdA(pc, m + 4);
    __builtin_amdgcn_s_setprio(1);
    #pragma unroll
    for (int m = 0; m < 4; ++m)
      #pragma unroll
      for (int n = 0; n < 4; ++n)
        acc[m + 4][n] = __builtin_amdgcn_mfma_f32_16x16x32_bf16(
            a[m], b[n], acc[m + 4][n], 0, 0, 0);
    __builtin_amdgcn_s_setprio(0);

    if (kt <= 29) { VMCNT(6); }        // drains stage(kt+1): next tile ready
    else if (kt == 30) { VMCNT(0); }   // tail: tile 31 fully landed
    __builtin_amdgcn_s_barrier();
    pc = pc == 2 ? 0 : pc + 1;
  }

  // Epilogue: acc -> LDS (bf16, [128 rows][136 cols], 2 half-phases) ->
  // coalesced 16B stores. All staging loads drained (vmcnt(0) at kt=30).
  const int seg = bn >> 3;  // 0:u 1:f 2:r (128-wide tiles lie in one segment)
  __bf16* outb = (seg == 0) ? U : ((seg == 1) ? FG : RG);
  const int segcol0 = (bn & 7) * 128;

  float bv[4];
  #pragma unroll
  for (int n = 0; n < 4; ++n)
    bv[n] = bias[seg * 1024 + segcol0 + wc * 64 + n * 16 + fr];

  const int lrow = tid >> 4;        // 0..15 (readback)
  const int chunk = tid & 15;       // 16B chunk within 256B row
  #pragma unroll 1
  for (int h = 0; h < 2; ++h) {
    __syncthreads();
    if (wm == h) {
      #pragma unroll
      for (int m = 0; m < 8; ++m)
        #pragma unroll
        for (int n = 0; n < 4; ++n)
          #pragma unroll
          for (int j = 0; j < 4; ++j) {
            float v = acc[m][n][j] + bv[n];
            if (seg != 0) v = sigmoidf_(v);
            lds[(m * 16 + fk * 4 + j) * 136 + wc * 64 + n * 16 + fr] =
                (__bf16)v;
          }
    }
    __syncthreads();
    #pragma unroll
    for (int it = 0; it < 8; ++it) {
      const int r = it * 16 + lrow;
      const bf16x8 val = *(const bf16x8*)(lds + r * 136 + chunk * 8);
      const size_t grow = (size_t)(bm * 256 + h * 128 + r);
      *(bf16x8*)(outb + grow * D_DIM + segcol0 + chunk * 8) = val;
    }
  }
}

// ---------------------------------------------------------------------------
// Scan pass A: per (chunk, bd) affine composition over CLEN steps.
// ---------------------------------------------------------------------------
__global__ __launch_bounds__(256) void scanA_kernel(
    const __bf16* __restrict__ fg, const __bf16* __restrict__ u,
    float* __restrict__ av) {
  const int ci = blockIdx.x;
  const int bd = blockIdx.y * 256 + threadIdx.x;
  float a = 1.0f, v = 0.0f;
  const size_t base = (size_t)ci * CLEN * BD + bd;
  #pragma unroll 8
  for (int i = 0; i < CLEN; ++i) {
    const size_t idx = base + (size_t)i * BD;
    const float f = (float)fg[idx];
    const float uu = (float)u[idx];
    a *= f;
    v = f * v + (1.0f - f) * uu;
  }
  av[(size_t)ci * BD + bd] = a;
  av[(size_t)NCHUNK * BD + (size_t)ci * BD + bd] = v;
}

// ---------------------------------------------------------------------------
// Scan pass B: sequential combine across chunks; writes last_c.
// ---------------------------------------------------------------------------
__global__ __launch_bounds__(256) void scanB_kernel(
    const float* __restrict__ av, const float* __restrict__ c0,
    float* __restrict__ carries, float* __restrict__ out1) {
  const int bd = blockIdx.x * 256 + threadIdx.x;
  float c = c0[bd];
  #pragma unroll 8
  for (int ci = 0; ci < NCHUNK; ++ci) {
    carries[(size_t)ci * BD + bd] = c;
    c = av[(size_t)ci * BD + bd] * c + av[(size_t)NCHUNK * BD + (size_t)ci * BD + bd];
  }
  out1[bd] = c;
}

// ---------------------------------------------------------------------------
// Scan pass C: re-run recurrence within chunk, fuse hs + residual.
// ---------------------------------------------------------------------------
__global__ __launch_bounds__(256) void scanC_kernel(
    const __bf16* __restrict__ fg, const __bf16* __restrict__ u,
    const __bf16* __restrict__ rg, const __bf16* __restrict__ xn,
    const float* __restrict__ x, const float* __restrict__ carries,
    float* __restrict__ out0) {
  const int ci = blockIdx.x;
  const int bd = blockIdx.y * 256 + threadIdx.x;
  float c = carries[(size_t)ci * BD + bd];
  const size_t base = (size_t)ci * CLEN * BD + bd;
  #pragma unroll 4
  for (int i = 0; i < CLEN; ++i) {
    const size_t idx = base + (size_t)i * BD;
    const float f = (float)fg[idx];
    const float uu = (float)u[idx];
    c = f * c + (1.0f - f) * uu;
    const float r = (float)rg[idx];
    const float xnv = (float)xn[idx];
    const float hs = r * tanhf(c) + (1.0f - r) * xnv;
    out0[idx] = x[idx] + hs;
  }
}

// ---------------------------------------------------------------------------
extern "C" void kernel_launch(void* const* d_in, const int* in_sizes, int n_in,
                              void* d_out, int out_size, void* d_ws,
                              size_t ws_size, hipStream_t stream) {
  const float* x     = (const float*)d_in[0];
  const float* c0    = (const float*)d_in[1];
  const float* W     = (const float*)d_in[2];
  const float* bias  = (const float*)d_in[3];
  const float* gamma = (const float*)d_in[4];
  const float* beta  = (const float*)d_in[5];

  float* out0 = (float*)d_out;                 // [L,B,D]
  float* out1 = out0 + (size_t)M_DIM * D_DIM;  // [B,D]

  char* ws = (char*)d_ws;
  __bf16* xn = (__bf16*)(ws + 0);              // 32 MB
  __bf16* Wb = (__bf16*)(ws + 33554432);       //  6 MB
  __bf16* U  = (__bf16*)(ws + 39845888);       // 32 MB
  __bf16* FG = (__bf16*)(ws + 73400320);       // 32 MB
  __bf16* RG = (__bf16*)(ws + 106954752);      // 32 MB
  float* av      = (float*)(ws + 140509184);   //  4 MB
  float* carries = (float*)(ws + 144703488);   //  2 MB

  ln_kernel<<<M_DIM, 256, 0, stream>>>(x, gamma, beta, xn);
  wconv_kernel<<<(N_DIM * K_DIM / 4) / 256, 256, 0, stream>>>(W, Wb);
  gemm256_kernel<<<(M_DIM / 256) * (N_DIM / 128), 256, 0, stream>>>(
      xn, Wb, bias, U, FG, RG);
  scanA_kernel<<<dim3(NCHUNK, BD / 256), 256, 0, stream>>>(FG, U, av);
  scanB_kernel<<<BD / 256, 256, 0, stream>>>(av, c0, carries, out1);
  scanC_kernel<<<dim3(NCHUNK, BD / 256), 256, 0, stream>>>(
      FG, U, RG, xn, x, carries, out0);
}

// Round 7
// 221.604 us; speedup vs baseline: 5.2665x; 1.0279x over previous
//
#include <hip/hip_runtime.h>
#include <hip/hip_bf16.h>

// Problem dims (fixed by reference)
#define L_DIM 2048
#define B_DIM 8
#define D_DIM 1024
#define M_DIM (L_DIM * B_DIM)   // 16384 rows of x_norm
#define N_DIM (3 * D_DIM)       // 3072
#define K_DIM D_DIM             // 1024
#define BD (B_DIM * D_DIM)      // 8192 independent recurrence chains
#define NCHUNK 64
#define CLEN (L_DIM / NCHUNK)   // 32

typedef __attribute__((ext_vector_type(8))) __bf16 bf16x8;
typedef __attribute__((ext_vector_type(4))) __bf16 bf16x4;
typedef __attribute__((ext_vector_type(4))) float f32x4;

#define GLOAD_LDS16(g, l)                                        \
  __builtin_amdgcn_global_load_lds(                              \
      (const __attribute__((address_space(1))) void*)(g),        \
      (__attribute__((address_space(3))) void*)(l), 16, 0, 0)

__device__ __forceinline__ float sigmoidf_(float v) {
  return 1.0f / (1.0f + __expf(-v));
}

// ---------------------------------------------------------------------------
// Kernel 1: LayerNorm per (l,b) row of D=1024.
// ---------------------------------------------------------------------------
__global__ __launch_bounds__(256) void ln_kernel(
    const float* __restrict__ x, const float* __restrict__ gamma,
    const float* __restrict__ beta, __bf16* __restrict__ xn) {
  const int row = blockIdx.x;
  const int tid = threadIdx.x;
  const float4 v = ((const float4*)(x + (size_t)row * D_DIM))[tid];
  float s  = v.x + v.y + v.z + v.w;
  float ss = v.x * v.x + v.y * v.y + v.z * v.z + v.w * v.w;
  #pragma unroll
  for (int off = 32; off > 0; off >>= 1) {
    s  += __shfl_xor(s, off);
    ss += __shfl_xor(ss, off);
  }
  __shared__ float sb[8];
  const int wid = tid >> 6, lane = tid & 63;
  if (lane == 0) { sb[wid] = s; sb[4 + wid] = ss; }
  __syncthreads();
  const float tot  = sb[0] + sb[1] + sb[2] + sb[3];
  const float tot2 = sb[4] + sb[5] + sb[6] + sb[7];
  const float mu  = tot * (1.0f / D_DIM);
  const float var = tot2 * (1.0f / D_DIM) - mu * mu;
  const float rstd = rsqrtf(var + 1e-5f);
  const float4 g  = ((const float4*)gamma)[tid];
  const float4 bt = ((const float4*)beta)[tid];
  bf16x4 o;
  o[0] = (__bf16)((v.x - mu) * rstd * g.x + bt.x);
  o[1] = (__bf16)((v.y - mu) * rstd * g.y + bt.y);
  o[2] = (__bf16)((v.z - mu) * rstd * g.z + bt.z);
  o[3] = (__bf16)((v.w - mu) * rstd * g.w + bt.w);
  ((bf16x4*)(xn + (size_t)row * D_DIM))[tid] = o;
}

// ---------------------------------------------------------------------------
// Kernel 2: W fp32 -> bf16
// ---------------------------------------------------------------------------
__global__ __launch_bounds__(256) void wconv_kernel(
    const float* __restrict__ W, __bf16* __restrict__ Wb) {
  const size_t i = ((size_t)blockIdx.x * 256 + threadIdx.x) * 4;
  const float4 v = *(const float4*)(W + i);
  bf16x4 o;
  o[0] = (__bf16)v.x; o[1] = (__bf16)v.y; o[2] = (__bf16)v.z; o[3] = (__bf16)v.w;
  *(bf16x4*)(Wb + i) = o;
}

// ---------------------------------------------------------------------------
// Kernel 3: 256x128 GEMM, BK=32, triple-buffered, STATIC mod-3 unroll.
//
// Geometry = round-5 best (144 us): 8 waves 4x2, per-wave 64x64 acc[4][4]
// (64 VGPR -> 16 waves/CU), LDS 72 KB -> 2 blocks/CU.
// Change 1: main loop statically unrolled 10 x 3 tiles (+2 tail) so every
// LDS base (bufs 0/1/2) and global stage offset (kt*64B <= 1984, 13-bit imm)
// is compile-time -> kills dynamic pc/ps VALU chains (VALUBusy 35%).
// Change 2: corrected counted wait. Stage set = 3 vmem INSTRS per thread
// (2 A + 1 B). Ledger: entering tile t, outstanding = S(t+1) [3]; issue
// S(t+2) -> 6; VMCNT(3) at tile end drains S(t+1) exactly -> tile t+1's
// buffer guaranteed landed. Tail: end of t=30 VMCNT(0); t=31 no wait.
// WAR: S(t+2) writes buf (t+2)%3, last read at tile t-1, ordered by t-1's
// trailing barrier. Prologue: S(0),S(1); VMCNT(3); barrier.
//
// Staging/swizzle (measured ~0 conflicts r3-r6): chunk row=tid>>2,
// slot=(tid&3)^((row>>1)&3), XOR on global SOURCE, LDS linear; frag reads
// apply the same XOR (swz). Global: 16 rows x 64 B contiguous per instr.
// ---------------------------------------------------------------------------
#define VMCNT(n) asm volatile("s_waitcnt vmcnt(" #n ")" ::: "memory")

__global__ __launch_bounds__(512, 4) void gemm256_kernel(
    const __bf16* __restrict__ A,   // [M][K]
    const __bf16* __restrict__ Bm,  // [N][K]
    const float* __restrict__ bias,
    __bf16* __restrict__ U, __bf16* __restrict__ FG, __bf16* __restrict__ RG) {
  __shared__ __bf16 lds[36864];   // 72 KB; epilogue reuses first 34.8 KB
  const int tid = threadIdx.x;
  const int lane = tid & 63;
  const int wid = tid >> 6;       // 0..7
  const int wq = wid >> 1;        // 0..3  row quarter (64 rows)
  const int wc = wid & 1;         // 0..1  col half   (64 cols)

  // XCD-bijective swizzle: 1536 blocks, 1536 % 8 == 0. bn fastest -> the 24
  // blocks sharing an A panel are consecutive on one XCD (A panel L2-hot).
  const int bid0 = blockIdx.x;
  const int bid = (bid0 & 7) * 192 + (bid0 >> 3);
  const int bm = bid / 24, bn = bid % 24;

  const int srow  = tid >> 2;                       // 0..127
  const int sslot = (tid & 3) ^ ((srow >> 1) & 3);  // swizzled 16B slot
  const __bf16* aBase0 = A + (size_t)(bm * 256 + srow) * K_DIM + sslot * 8;
  const __bf16* aBase1 = aBase0 + (size_t)128 * K_DIM;
  const __bf16* bBase  = Bm + (size_t)(bn * 128 + srow) * K_DIM + sslot * 8;

  // Stage tile kt into buf p (p compile-time at every call site).
  auto stage = [&](int kt, int p) {
    GLOAD_LDS16(aBase0 + kt * 32, lds + p * 12288 + tid * 8);
    GLOAD_LDS16(aBase1 + kt * 32, lds + p * 12288 + (tid + 512) * 8);
    GLOAD_LDS16(bBase + kt * 32, lds + p * 12288 + 8192 + tid * 8);
  };

  const int fr = lane & 15, fk = lane >> 4;
  const int swz = fk ^ ((fr >> 1) & 3);             // undo source swizzle
  auto rdA = [&](int p, int m) {
    return *(const bf16x8*)(lds + p * 12288 +
                            (wq * 64 + m * 16 + fr) * 32 + swz * 8);
  };
  auto rdB = [&](int p, int n) {
    return *(const bf16x8*)(lds + p * 12288 + 8192 +
                            (wc * 64 + n * 16 + fr) * 32 + swz * 8);
  };

  f32x4 acc[4][4] = {};

  auto tileCompute = [&](int p) {   // p compile-time at every call site
    bf16x8 a[4], b[4];
    #pragma unroll
    for (int m = 0; m < 4; ++m) a[m] = rdA(p, m);
    #pragma unroll
    for (int n = 0; n < 4; ++n) b[n] = rdB(p, n);
    __builtin_amdgcn_s_setprio(1);
    #pragma unroll
    for (int m = 0; m < 4; ++m)
      #pragma unroll
      for (int n = 0; n < 4; ++n)
        acc[m][n] = __builtin_amdgcn_mfma_f32_16x16x32_bf16(a[m], b[n],
                                                            acc[m][n], 0, 0, 0);
    __builtin_amdgcn_s_setprio(0);
  };

  // Prologue: stage tiles 0,1. VMCNT(3): S(0) landed, S(1) in flight.
  stage(0, 0); stage(1, 1);
  VMCNT(3);
  __builtin_amdgcn_s_barrier();

  // Main: 10 iters x 3 tiles (t0%3==0 -> bufs 0,1,2 static). Stages 2..31.
  #pragma unroll 1
  for (int i = 0; i < 10; ++i) {
    const int t0 = i * 3;
    stage(t0 + 2, 2);
    tileCompute(0);
    VMCNT(3);
    __builtin_amdgcn_s_barrier();
    stage(t0 + 3, 0);
    tileCompute(1);
    VMCNT(3);
    __builtin_amdgcn_s_barrier();
    stage(t0 + 4, 1);
    tileCompute(2);
    VMCNT(3);
    __builtin_amdgcn_s_barrier();
  }
  // Tail: tile 30 (buf 0), tile 31 (buf 1).
  tileCompute(0);
  VMCNT(0);                       // S(31) fully landed
  __builtin_amdgcn_s_barrier();
  tileCompute(1);

  // Epilogue: acc -> LDS (bf16, [128 rows][136 cols], 2 half-phases) ->
  // coalesced 16B stores. All staging loads drained (VMCNT(0) above).
  const int seg = bn >> 3;  // 0:u 1:f 2:r (128-wide tiles lie in one segment)
  __bf16* outb = (seg == 0) ? U : ((seg == 1) ? FG : RG);
  const int segcol0 = (bn & 7) * 128;

  float bv[4];
  #pragma unroll
  for (int n = 0; n < 4; ++n)
    bv[n] = bias[seg * 1024 + segcol0 + wc * 64 + n * 16 + fr];

  const int lrow = tid >> 4;        // 0..31 (readback)
  const int chunk = tid & 15;       // 16B chunk within 256B row
  #pragma unroll 1
  for (int h = 0; h < 2; ++h) {
    __syncthreads();
    if ((wq >> 1) == h) {
      const int lr0 = (wq & 1) * 64 + fk * 4;
      #pragma unroll
      for (int m = 0; m < 4; ++m)
        #pragma unroll
        for (int n = 0; n < 4; ++n)
          #pragma unroll
          for (int j = 0; j < 4; ++j) {
            float v = acc[m][n][j] + bv[n];
            if (seg != 0) v = sigmoidf_(v);
            lds[(lr0 + m * 16 + j) * 136 + wc * 64 + n * 16 + fr] = (__bf16)v;
          }
    }
    __syncthreads();
    #pragma unroll
    for (int it = 0; it < 4; ++it) {
      const int r = it * 32 + lrow;
      const bf16x8 val = *(const bf16x8*)(lds + r * 136 + chunk * 8);
      const size_t grow = (size_t)(bm * 256 + h * 128 + r);
      *(bf16x8*)(outb + grow * D_DIM + segcol0 + chunk * 8) = val;
    }
  }
}

// ---------------------------------------------------------------------------
// Scan pass A: per (chunk, bd) affine composition over CLEN steps.
// ---------------------------------------------------------------------------
__global__ __launch_bounds__(256) void scanA_kernel(
    const __bf16* __restrict__ fg, const __bf16* __restrict__ u,
    float* __restrict__ av) {
  const int ci = blockIdx.x;
  const int bd = blockIdx.y * 256 + threadIdx.x;
  float a = 1.0f, v = 0.0f;
  const size_t base = (size_t)ci * CLEN * BD + bd;
  #pragma unroll 8
  for (int i = 0; i < CLEN; ++i) {
    const size_t idx = base + (size_t)i * BD;
    const float f = (float)fg[idx];
    const float uu = (float)u[idx];
    a *= f;
    v = f * v + (1.0f - f) * uu;
  }
  av[(size_t)ci * BD + bd] = a;
  av[(size_t)NCHUNK * BD + (size_t)ci * BD + bd] = v;
}

// ---------------------------------------------------------------------------
// Scan pass B: sequential combine across chunks; writes last_c.
// ---------------------------------------------------------------------------
__global__ __launch_bounds__(256) void scanB_kernel(
    const float* __restrict__ av, const float* __restrict__ c0,
    float* __restrict__ carries, float* __restrict__ out1) {
  const int bd = blockIdx.x * 256 + threadIdx.x;
  float c = c0[bd];
  #pragma unroll 8
  for (int ci = 0; ci < NCHUNK; ++ci) {
    carries[(size_t)ci * BD + bd] = c;
    c = av[(size_t)ci * BD + bd] * c + av[(size_t)NCHUNK * BD + (size_t)ci * BD + bd];
  }
  out1[bd] = c;
}

// ---------------------------------------------------------------------------
// Scan pass C: re-run recurrence within chunk, fuse hs + residual.
// ---------------------------------------------------------------------------
__global__ __launch_bounds__(256) void scanC_kernel(
    const __bf16* __restrict__ fg, const __bf16* __restrict__ u,
    const __bf16* __restrict__ rg, const __bf16* __restrict__ xn,
    const float* __restrict__ x, const float* __restrict__ carries,
    float* __restrict__ out0) {
  const int ci = blockIdx.x;
  const int bd = blockIdx.y * 256 + threadIdx.x;
  float c = carries[(size_t)ci * BD + bd];
  const size_t base = (size_t)ci * CLEN * BD + bd;
  #pragma unroll 4
  for (int i = 0; i < CLEN; ++i) {
    const size_t idx = base + (size_t)i * BD;
    const float f = (float)fg[idx];
    const float uu = (float)u[idx];
    c = f * c + (1.0f - f) * uu;
    const float r = (float)rg[idx];
    const float xnv = (float)xn[idx];
    const float hs = r * tanhf(c) + (1.0f - r) * xnv;
    out0[idx] = x[idx] + hs;
  }
}

// ---------------------------------------------------------------------------
extern "C" void kernel_launch(void* const* d_in, const int* in_sizes, int n_in,
                              void* d_out, int out_size, void* d_ws,
                              size_t ws_size, hipStream_t stream) {
  const float* x     = (const float*)d_in[0];
  const float* c0    = (const float*)d_in[1];
  const float* W     = (const float*)d_in[2];
  const float* bias  = (const float*)d_in[3];
  const float* gamma = (const float*)d_in[4];
  const float* beta  = (const float*)d_in[5];

  float* out0 = (float*)d_out;                 // [L,B,D]
  float* out1 = out0 + (size_t)M_DIM * D_DIM;  // [B,D]

  char* ws = (char*)d_ws;
  __bf16* xn = (__bf16*)(ws + 0);              // 32 MB
  __bf16* Wb = (__bf16*)(ws + 33554432);       //  6 MB
  __bf16* U  = (__bf16*)(ws + 39845888);       // 32 MB
  __bf16* FG = (__bf16*)(ws + 73400320);       // 32 MB
  __bf16* RG = (__bf16*)(ws + 106954752);      // 32 MB
  float* av      = (float*)(ws + 140509184);   //  4 MB
  float* carries = (float*)(ws + 144703488);   //  2 MB

  ln_kernel<<<M_DIM, 256, 0, stream>>>(x, gamma, beta, xn);
  wconv_kernel<<<(N_DIM * K_DIM / 4) / 256, 256, 0, stream>>>(W, Wb);
  gemm256_kernel<<<(M_DIM / 256) * (N_DIM / 128), 512, 0, stream>>>(
      xn, Wb, bias, U, FG, RG);
  scanA_kernel<<<dim3(NCHUNK, BD / 256), 256, 0, stream>>>(FG, U, av);
  scanB_kernel<<<BD / 256, 256, 0, stream>>>(av, c0, carries, out1);
  scanC_kernel<<<dim3(NCHUNK, BD / 256), 256, 0, stream>>>(
      FG, U, RG, xn, x, carries, out0);
}

// Round 8
// 215.958 us; speedup vs baseline: 5.4042x; 1.0261x over previous
//
#include <hip/hip_runtime.h>
#include <hip/hip_bf16.h>

// Problem dims (fixed by reference)
#define L_DIM 2048
#define B_DIM 8
#define D_DIM 1024
#define M_DIM (L_DIM * B_DIM)   // 16384 rows of x_norm
#define N_DIM (3 * D_DIM)       // 3072
#define K_DIM D_DIM             // 1024
#define BD (B_DIM * D_DIM)      // 8192 independent recurrence chains
#define NCHUNK 64
#define CLEN (L_DIM / NCHUNK)   // 32

typedef __attribute__((ext_vector_type(8))) __bf16 bf16x8;
typedef __attribute__((ext_vector_type(4))) __bf16 bf16x4;
typedef __attribute__((ext_vector_type(4))) float f32x4;

#define GLOAD_LDS16(g, l)                                        \
  __builtin_amdgcn_global_load_lds(                              \
      (const __attribute__((address_space(1))) void*)(g),        \
      (__attribute__((address_space(3))) void*)(l), 16, 0, 0)

__device__ __forceinline__ float sigmoidf_(float v) {
  return 1.0f / (1.0f + __expf(-v));
}

// ---------------------------------------------------------------------------
// Kernel 1: LayerNorm per (l,b) row of D=1024.
// ---------------------------------------------------------------------------
__global__ __launch_bounds__(256) void ln_kernel(
    const float* __restrict__ x, const float* __restrict__ gamma,
    const float* __restrict__ beta, __bf16* __restrict__ xn) {
  const int row = blockIdx.x;
  const int tid = threadIdx.x;
  const float4 v = ((const float4*)(x + (size_t)row * D_DIM))[tid];
  float s  = v.x + v.y + v.z + v.w;
  float ss = v.x * v.x + v.y * v.y + v.z * v.z + v.w * v.w;
  #pragma unroll
  for (int off = 32; off > 0; off >>= 1) {
    s  += __shfl_xor(s, off);
    ss += __shfl_xor(ss, off);
  }
  __shared__ float sb[8];
  const int wid = tid >> 6, lane = tid & 63;
  if (lane == 0) { sb[wid] = s; sb[4 + wid] = ss; }
  __syncthreads();
  const float tot  = sb[0] + sb[1] + sb[2] + sb[3];
  const float tot2 = sb[4] + sb[5] + sb[6] + sb[7];
  const float mu  = tot * (1.0f / D_DIM);
  const float var = tot2 * (1.0f / D_DIM) - mu * mu;
  const float rstd = rsqrtf(var + 1e-5f);
  const float4 g  = ((const float4*)gamma)[tid];
  const float4 bt = ((const float4*)beta)[tid];
  bf16x4 o;
  o[0] = (__bf16)((v.x - mu) * rstd * g.x + bt.x);
  o[1] = (__bf16)((v.y - mu) * rstd * g.y + bt.y);
  o[2] = (__bf16)((v.z - mu) * rstd * g.z + bt.z);
  o[3] = (__bf16)((v.w - mu) * rstd * g.w + bt.w);
  ((bf16x4*)(xn + (size_t)row * D_DIM))[tid] = o;
}

// ---------------------------------------------------------------------------
// Kernel 2: W fp32 -> bf16
// ---------------------------------------------------------------------------
__global__ __launch_bounds__(256) void wconv_kernel(
    const float* __restrict__ W, __bf16* __restrict__ Wb) {
  const size_t i = ((size_t)blockIdx.x * 256 + threadIdx.x) * 4;
  const float4 v = *(const float4*)(W + i);
  bf16x4 o;
  o[0] = (__bf16)v.x; o[1] = (__bf16)v.y; o[2] = (__bf16)v.z; o[3] = (__bf16)v.w;
  *(bf16x4*)(Wb + i) = o;
}

// ---------------------------------------------------------------------------
// Kernel 3: 128x128 GEMM, BK=64, SINGLE-buffer m97 structure.
//
// Rationale (r7 post-mortem): the 2-block/CU shallow pipeline plateaus at
// ~750 TF (matrix pipe 34%, rest barrier/drain serialization). m97-exact
// structure is externally measured at 874-912 TF on this chip: 32 KB single
// buffer -> ~3 blocks/CU (VGPR ~165, 12 waves/CU); the vmcnt(0)+barrier
// drain of one block is hidden by 2-3 sibling blocks (m114 overlap), and
// BK=64 halves sync events per FLOP vs r7's BK=32.
//
// Per K-tile: __syncthreads (WAR: prev reads done) -> stage (8 x
// global_load_lds w16 per thread) -> __syncthreads (compiler emits
// vmcnt(0) drain) -> compute (16 ds_read_b128 + 32 MFMA per wave).
//
// Swizzle (proven r3-r7, ~0 conflicts): unit [128 rows][8 slots of 16B];
// stage chunk c: row=c>>3, LDS linear dest, global src slot = (c&7)^(row&7);
// frag read slot = (kk*4+fk)^(fr&7) -> <=2-way bank aliasing (free).
// Global: 8 rows x 128B contiguous per wave instr (perfect coalescing).
// ---------------------------------------------------------------------------
__global__ __launch_bounds__(256) void gemm_kernel(
    const __bf16* __restrict__ A,   // [M][K]
    const __bf16* __restrict__ Bm,  // [N][K]
    const float* __restrict__ bias,
    __bf16* __restrict__ U, __bf16* __restrict__ FG, __bf16* __restrict__ RG) {
  __shared__ __bf16 lds[17408];   // 34.8 KB (tiles use 32 KB; epilogue 34.8)
  const int tid = threadIdx.x;
  const int lane = tid & 63;
  const int wid = tid >> 6;       // 0..3
  const int wm = wid >> 1;        // 0..1  row half (64 rows)
  const int wc = wid & 1;         // 0..1  col half (64 cols)

  // XCD-bijective swizzle: 3072 blocks, 3072 % 8 == 0. bn fastest -> the 24
  // blocks sharing an A panel are consecutive on one XCD (A panel L2-hot).
  const int bid0 = blockIdx.x;
  const int bid = (bid0 & 7) * 384 + (bid0 >> 3);
  const int bm = bid / 24, bn = bid % 24;

  // Staging: A unit 128x64 at lds[0], B unit at lds[8192]. 1024 chunks each;
  // thread covers c = tid + 256*i (i=0..3). row = c>>3 (row&7 invariant in i),
  // src slot = (tid&7)^((tid>>3)&7).
  const int srow  = tid >> 3;                       // 0..31
  const int sslot = (tid & 7) ^ (srow & 7);         // swizzled 16B slot
  const __bf16* aSrc = A + (size_t)(bm * 128 + srow) * K_DIM + sslot * 8;
  const __bf16* bSrc = Bm + (size_t)(bn * 128 + srow) * K_DIM + sslot * 8;

  const int fr = lane & 15, fk = lane >> 4;
  const int swzbase = fk ^ (fr & 7);  // slot for kk=0; kk=1 adds XOR 4
  auto rdA = [&](int kk, int m) {
    return *(const bf16x8*)(lds + (wm * 64 + m * 16 + fr) * 64 +
                            ((kk * 4) ^ swzbase) * 8);
  };
  auto rdB = [&](int kk, int n) {
    return *(const bf16x8*)(lds + 8192 + (wc * 64 + n * 16 + fr) * 64 +
                            ((kk * 4) ^ swzbase) * 8);
  };

  f32x4 acc[4][4] = {};

  #pragma unroll 1
  for (int kt = 0; kt < 16; ++kt) {
    __syncthreads();                 // WAR: previous tile's reads complete
    #pragma unroll
    for (int i = 0; i < 4; ++i) {
      GLOAD_LDS16(aSrc + (size_t)(32 * i) * K_DIM + kt * 64,
                  lds + (tid + 256 * i) * 8);
      GLOAD_LDS16(bSrc + (size_t)(32 * i) * K_DIM + kt * 64,
                  lds + 8192 + (tid + 256 * i) * 8);
    }
    __syncthreads();                 // drains vmcnt(0): tile visible

    #pragma unroll
    for (int kk = 0; kk < 2; ++kk) {
      bf16x8 a[4], b[4];
      #pragma unroll
      for (int m = 0; m < 4; ++m) a[m] = rdA(kk, m);
      #pragma unroll
      for (int n = 0; n < 4; ++n) b[n] = rdB(kk, n);
      __builtin_amdgcn_s_setprio(1);
      #pragma unroll
      for (int m = 0; m < 4; ++m)
        #pragma unroll
        for (int n = 0; n < 4; ++n)
          acc[m][n] = __builtin_amdgcn_mfma_f32_16x16x32_bf16(
              a[m], b[n], acc[m][n], 0, 0, 0);
      __builtin_amdgcn_s_setprio(0);
    }
  }

  // Epilogue: acc -> LDS (bf16, [128 rows][136 cols]) -> coalesced stores.
  const int seg = bn >> 3;  // 0:u 1:f 2:r (128-wide tiles lie in one segment)
  __bf16* outb = (seg == 0) ? U : ((seg == 1) ? FG : RG);
  const int segcol0 = (bn & 7) * 128;

  float bv[4];
  #pragma unroll
  for (int n = 0; n < 4; ++n)
    bv[n] = bias[seg * 1024 + segcol0 + wc * 64 + n * 16 + fr];

  __syncthreads();   // tile reads done before overwriting LDS with output
  #pragma unroll
  for (int m = 0; m < 4; ++m)
    #pragma unroll
    for (int n = 0; n < 4; ++n)
      #pragma unroll
      for (int j = 0; j < 4; ++j) {
        float v = acc[m][n][j] + bv[n];
        if (seg != 0) v = sigmoidf_(v);
        lds[(wm * 64 + m * 16 + fk * 4 + j) * 136 + wc * 64 + n * 16 + fr] =
            (__bf16)v;
      }
  __syncthreads();
  const int lrow = tid >> 4;        // 0..15 (readback)
  const int chunk = tid & 15;       // 16B chunk within 256B row
  #pragma unroll
  for (int it = 0; it < 8; ++it) {
    const int r = it * 16 + lrow;
    const bf16x8 val = *(const bf16x8*)(lds + r * 136 + chunk * 8);
    const size_t grow = (size_t)(bm * 128 + r);
    *(bf16x8*)(outb + grow * D_DIM + segcol0 + chunk * 8) = val;
  }
}

// ---------------------------------------------------------------------------
// Scan pass A: per (chunk, bd) affine composition over CLEN steps.
// ---------------------------------------------------------------------------
__global__ __launch_bounds__(256) void scanA_kernel(
    const __bf16* __restrict__ fg, const __bf16* __restrict__ u,
    float* __restrict__ av) {
  const int ci = blockIdx.x;
  const int bd = blockIdx.y * 256 + threadIdx.x;
  float a = 1.0f, v = 0.0f;
  const size_t base = (size_t)ci * CLEN * BD + bd;
  #pragma unroll 8
  for (int i = 0; i < CLEN; ++i) {
    const size_t idx = base + (size_t)i * BD;
    const float f = (float)fg[idx];
    const float uu = (float)u[idx];
    a *= f;
    v = f * v + (1.0f - f) * uu;
  }
  av[(size_t)ci * BD + bd] = a;
  av[(size_t)NCHUNK * BD + (size_t)ci * BD + bd] = v;
}

// ---------------------------------------------------------------------------
// Scan pass B: sequential combine across chunks; writes last_c.
// ---------------------------------------------------------------------------
__global__ __launch_bounds__(256) void scanB_kernel(
    const float* __restrict__ av, const float* __restrict__ c0,
    float* __restrict__ carries, float* __restrict__ out1) {
  const int bd = blockIdx.x * 256 + threadIdx.x;
  float c = c0[bd];
  #pragma unroll 8
  for (int ci = 0; ci < NCHUNK; ++ci) {
    carries[(size_t)ci * BD + bd] = c;
    c = av[(size_t)ci * BD + bd] * c + av[(size_t)NCHUNK * BD + (size_t)ci * BD + bd];
  }
  out1[bd] = c;
}

// ---------------------------------------------------------------------------
// Scan pass C: re-run recurrence within chunk, fuse hs + residual.
// ---------------------------------------------------------------------------
__global__ __launch_bounds__(256) void scanC_kernel(
    const __bf16* __restrict__ fg, const __bf16* __restrict__ u,
    const __bf16* __restrict__ rg, const __bf16* __restrict__ xn,
    const float* __restrict__ x, const float* __restrict__ carries,
    float* __restrict__ out0) {
  const int ci = blockIdx.x;
  const int bd = blockIdx.y * 256 + threadIdx.x;
  float c = carries[(size_t)ci * BD + bd];
  const size_t base = (size_t)ci * CLEN * BD + bd;
  #pragma unroll 4
  for (int i = 0; i < CLEN; ++i) {
    const size_t idx = base + (size_t)i * BD;
    const float f = (float)fg[idx];
    const float uu = (float)u[idx];
    c = f * c + (1.0f - f) * uu;
    const float r = (float)rg[idx];
    const float xnv = (float)xn[idx];
    const float hs = r * tanhf(c) + (1.0f - r) * xnv;
    out0[idx] = x[idx] + hs;
  }
}

// ---------------------------------------------------------------------------
extern "C" void kernel_launch(void* const* d_in, const int* in_sizes, int n_in,
                              void* d_out, int out_size, void* d_ws,
                              size_t ws_size, hipStream_t stream) {
  const float* x     = (const float*)d_in[0];
  const float* c0    = (const float*)d_in[1];
  const float* W     = (const float*)d_in[2];
  const float* bias  = (const float*)d_in[3];
  const float* gamma = (const float*)d_in[4];
  const float* beta  = (const float*)d_in[5];

  float* out0 = (float*)d_out;                 // [L,B,D]
  float* out1 = out0 + (size_t)M_DIM * D_DIM;  // [B,D]

  char* ws = (char*)d_ws;
  __bf16* xn = (__bf16*)(ws + 0);              // 32 MB
  __bf16* Wb = (__bf16*)(ws + 33554432);       //  6 MB
  __bf16* U  = (__bf16*)(ws + 39845888);       // 32 MB
  __bf16* FG = (__bf16*)(ws + 73400320);       // 32 MB
  __bf16* RG = (__bf16*)(ws + 106954752);      // 32 MB
  float* av      = (float*)(ws + 140509184);   //  4 MB
  float* carries = (float*)(ws + 144703488);   //  2 MB

  ln_kernel<<<M_DIM, 256, 0, stream>>>(x, gamma, beta, xn);
  wconv_kernel<<<(N_DIM * K_DIM / 4) / 256, 256, 0, stream>>>(W, Wb);
  gemm_kernel<<<(M_DIM / 128) * (N_DIM / 128), 256, 0, stream>>>(
      xn, Wb, bias, U, FG, RG);
  scanA_kernel<<<dim3(NCHUNK, BD / 256), 256, 0, stream>>>(FG, U, av);
  scanB_kernel<<<BD / 256, 256, 0, stream>>>(av, c0, carries, out1);
  scanC_kernel<<<dim3(NCHUNK, BD / 256), 256, 0, stream>>>(
      FG, U, RG, xn, x, carries, out0);
}